// Round 7
// baseline (531.963 us; speedup 1.0000x reference)
//
#include <hip/hip_runtime.h>
#include <stdint.h>

#define BB 2
#define SS 2048
#define DD 1024
#define HH 8
#define HD 128
#define TOPK 32
#define ROWS (BB*HH*SS)   // 32768
#define BH 16
#define NCVT (BB*SS)      // 4096

typedef float f32x4 __attribute__((ext_vector_type(4)));
typedef _Float16 f16x8 __attribute__((ext_vector_type(8)));
typedef _Float16 f16x4 __attribute__((ext_vector_type(4)));

// ---------------------------------------------------------------- K1: cvt + top-32
// blocks [0, 4096): k,v fp32 -> head-major fp16 (light: no LDS, few regs)
// blocks [4096, 36864): top-32 select (verified ballot-compaction logic)
// Both paths are resource-light so fusion costs no occupancy (round-5 lesson:
// only fuse paths with matching footprints).
__global__ __launch_bounds__(256) void topk_cvt_kernel(const float* __restrict__ aw,
                                                       const float* __restrict__ k,
                                                       const float* __restrict__ v,
                                                       _Float16* __restrict__ k16,
                                                       _Float16* __restrict__ v16,
                                                       int* __restrict__ idx_out) {
    __shared__ int s_cnt;
    __shared__ int s_red[4];
    __shared__ unsigned long long s_cand[256];
    const int bid = blockIdx.x;
    const int t = threadIdx.x;

    if (bid < NCVT) {
        // ---------------- k,v fp32 -> fp16 head-major ----------------
        const int row = bid;                    // b*S + s
        const int b = row >> 11, s = row & 2047;
        const int h = t >> 5, d4 = (t & 31) * 4;
        const size_t src = (size_t)row * DD + t * 4;
        const size_t dst = ((size_t)(b * HH + h) * SS + s) * HD + d4;
        float4 f;
        f = *(const float4*)(k + src);
        *(f16x4*)(k16 + dst) = (f16x4){(_Float16)f.x,(_Float16)f.y,(_Float16)f.z,(_Float16)f.w};
        f = *(const float4*)(v + src);
        *(f16x4*)(v16 + dst) = (f16x4){(_Float16)f.x,(_Float16)f.y,(_Float16)f.z,(_Float16)f.w};
        return;
    }

    // ---------------- top-32 path (verified) ----------------
    const int row = bid - NCVT;
    const float* p = aw + (size_t)row * SS;
    float4 v0 = *(const float4*)(p + 4 * t);
    float4 v1 = *(const float4*)(p + 1024 + 4 * t);
    float vals[8] = {v0.x, v0.y, v0.z, v0.w, v1.x, v1.y, v1.z, v1.w};
    unsigned long long key[8];
#pragma unroll
    for (int i = 0; i < 8; i++) {
        int e = (i < 4) ? (4 * t + i) : (1024 + 4 * t + (i - 4));
        unsigned u = __float_as_uint(vals[i]);
        unsigned sk = (u & 0x80000000u) ? ~u : (u | 0x80000000u);
        key[i] = ((unsigned long long)sk << 11) | (unsigned)(2047 - e);
    }
    const int lane = t & 63, wv = t >> 6;
    const unsigned long long lmask = (lane == 63) ? ~0ull >> 1 : (1ull << lane) - 1;

    // N(0,1) quantile ~1.76 -> E[survivors] ~80, sigma ~9: always in [32,256]
    unsigned thr0 = __float_as_uint(1.76f) | 0x80000000u;
    unsigned long long T = ((unsigned long long)thr0 << 11) | 2047ull;

    if (t == 0) s_cnt = 0;
    __syncthreads();
#pragma unroll
    for (int i = 0; i < 8; i++) {
        bool pred = key[i] > T;
        unsigned long long m = __ballot(pred);
        int base = 0;
        if (lane == 0 && m) base = atomicAdd(&s_cnt, __popcll(m));
        base = __shfl(base, 0, 64);
        if (pred) {
            int pos = base + __popcll(m & lmask);
            if (pos < 256) s_cand[pos] = key[i];
        }
    }
    __syncthreads();

    if (s_cnt < TOPK || s_cnt > 256) {
        // rare fallback: bisect threshold until count in range, recompact
        unsigned long long lo = 0, hi = ~0ull;
        if (s_cnt > 256) lo = T; else hi = T;
        T = lo + ((hi - lo) >> 1);
        for (int it = 0; it < 40; ++it) {
            int c = 0;
#pragma unroll
            for (int i = 0; i < 8; i++) c += (key[i] > T) ? 1 : 0;
            for (int off = 32; off; off >>= 1) c += __shfl_down(c, off, 64);
            if (lane == 0) s_red[wv] = c;
            __syncthreads();
            int tot = s_red[0] + s_red[1] + s_red[2] + s_red[3];
            if (tot >= TOPK && tot <= 256) break;
            if (tot > 256) lo = T; else hi = T;
            T = lo + ((hi - lo) >> 1);
            __syncthreads();
        }
        if (t == 0) s_cnt = 0;
        __syncthreads();
#pragma unroll
        for (int i = 0; i < 8; i++) {
            bool pred = key[i] > T;
            unsigned long long m = __ballot(pred);
            int base = 0;
            if (lane == 0 && m) base = atomicAdd(&s_cnt, __popcll(m));
            base = __shfl(base, 0, 64);
            if (pred) {
                int pos = base + __popcll(m & lmask);
                if (pos < 256) s_cand[pos] = key[i];
            }
        }
        __syncthreads();
    }

    const int C = s_cnt < 256 ? s_cnt : 256;
    if (t < C) {
        unsigned long long mk = s_cand[t];
        int rank = 0;
        for (int j = 0; j < C; ++j)
            rank += (s_cand[j] > mk) ? 1 : 0;
        if (rank < TOPK)
            idx_out[(size_t)row * TOPK + rank] = 2047 - (int)(mk & 2047ull);
    }
}

// ------------------------------------------------------- K2: softmax stats
// (byte-identical to round-6 verified version)
__global__ __launch_bounds__(256) void stats_kernel(const float* __restrict__ q,
                                                    const float* __restrict__ k,
                                                    float* __restrict__ ws_m,
                                                    float* __restrict__ ws_l) {
    __shared__ __align__(16) _Float16 Ks[2][64 * 128];   // 2 x 16 KB
    const int bid = blockIdx.x;
    const int t = threadIdx.x;
    const int xcd = bid & 7;
    const int r = bid >> 3;
    const int bh = xcd * 2 + (r & 1);
    const int rr = r >> 1;
    const int qt = rr & 15;
    const int quarter = rr >> 4;          // 0..3: 512 keys each
    const int b = bh >> 3, h = bh & 7;
    const int wv = t >> 6, lane = t & 63;
    const int l16 = lane & 15, quad = lane >> 4;

    f16x8 af[2][4];
#pragma unroll
    for (int a = 0; a < 2; a++)
#pragma unroll
        for (int ks = 0; ks < 4; ks++) {
            const float* qs = q + (size_t)(b * SS + qt * 128 + wv * 32 + a * 16 + l16) * DD
                                + h * HD + ks * 32 + quad * 8;
            float4 f0 = *(const float4*)qs;
            float4 f1 = *(const float4*)(qs + 4);
            af[a][ks] = (f16x8){(_Float16)f0.x,(_Float16)f0.y,(_Float16)f0.z,(_Float16)f0.w,
                                (_Float16)f1.x,(_Float16)f1.y,(_Float16)f1.z,(_Float16)f1.w};
        }

    const int srow = t >> 2, cgrp = t & 3;
    const float* kb = k + (size_t)b * SS * DD + h * HD;

    int rdoff[4];
#pragma unroll
    for (int ks = 0; ks < 4; ks++)
        rdoff[ks] = (((ks * 4 + quad) ^ (l16 & 7)) * 8);

    float mrun[2][4], lrun[2][4];
#pragma unroll
    for (int a = 0; a < 2; a++)
#pragma unroll
        for (int r2 = 0; r2 < 4; r2++) { mrun[a][r2] = -INFINITY; lrun[a][r2] = 0.f; }

    {   // prologue: tile 0
        const float* src = kb + (size_t)(quarter * 8 * 64 + srow) * DD;
        float4 fr[8];
#pragma unroll
        for (int c = 0; c < 4; c++) {
            int cc = cgrp * 4 + c;
            fr[c * 2]     = *(const float4*)(src + cc * 8);
            fr[c * 2 + 1] = *(const float4*)(src + cc * 8 + 4);
        }
#pragma unroll
        for (int c = 0; c < 4; c++) {
            int cc = cgrp * 4 + c;
            f16x8 w = {(_Float16)fr[c*2].x,(_Float16)fr[c*2].y,(_Float16)fr[c*2].z,(_Float16)fr[c*2].w,
                       (_Float16)fr[c*2+1].x,(_Float16)fr[c*2+1].y,(_Float16)fr[c*2+1].z,(_Float16)fr[c*2+1].w};
            *(f16x8*)&Ks[0][srow * 128 + ((cc ^ (srow & 7)) * 8)] = w;
        }
    }
    __syncthreads();

    int cur = 0;
    for (int tt = 0; tt < 8; ++tt) {
        float4 nf[8];
        if (tt < 7) {
            const float* src = kb + (size_t)((quarter * 8 + tt + 1) * 64 + srow) * DD;
#pragma unroll
            for (int c = 0; c < 4; c++) {
                int cc = cgrp * 4 + c;
                nf[c * 2]     = *(const float4*)(src + cc * 8);
                nf[c * 2 + 1] = *(const float4*)(src + cc * 8 + 4);
            }
        }
        f32x4 acc[2][4];
#pragma unroll
        for (int a = 0; a < 2; a++)
#pragma unroll
            for (int n = 0; n < 4; n++) acc[a][n] = (f32x4){0.f, 0.f, 0.f, 0.f};
#pragma unroll
        for (int ks = 0; ks < 4; ++ks) {
            f16x8 bfr[4];
#pragma unroll
            for (int n = 0; n < 4; n++)
                bfr[n] = *(const f16x8*)&Ks[cur][(n * 16 + l16) * 128 + rdoff[ks]];
#pragma unroll
            for (int a = 0; a < 2; a++)
#pragma unroll
                for (int n = 0; n < 4; n++)
                    acc[a][n] = __builtin_amdgcn_mfma_f32_16x16x32_f16(af[a][ks], bfr[n], acc[a][n], 0, 0, 0);
        }
#pragma unroll
        for (int a = 0; a < 2; a++) {
#pragma unroll
            for (int r2 = 0; r2 < 4; r2++) {
                float tm = fmaxf(fmaxf(acc[a][0][r2], acc[a][1][r2]),
                                 fmaxf(acc[a][2][r2], acc[a][3][r2]));
#pragma unroll
                for (int off = 1; off < 16; off <<= 1) tm = fmaxf(tm, __shfl_xor(tm, off, 64));
                float tl = 0.f;
#pragma unroll
                for (int n = 0; n < 4; n++) tl += __expf(acc[a][n][r2] - tm);
#pragma unroll
                for (int off = 1; off < 16; off <<= 1) tl += __shfl_xor(tl, off, 64);
                float mo = mrun[a][r2];
                float mn = fmaxf(mo, tm);
                lrun[a][r2] = lrun[a][r2] * __expf(mo - mn) + tl * __expf(tm - mn);
                mrun[a][r2] = mn;
            }
        }
        if (tt < 7) {
#pragma unroll
            for (int c = 0; c < 4; c++) {
                int cc = cgrp * 4 + c;
                f16x8 w = {(_Float16)nf[c*2].x,(_Float16)nf[c*2].y,(_Float16)nf[c*2].z,(_Float16)nf[c*2].w,
                           (_Float16)nf[c*2+1].x,(_Float16)nf[c*2+1].y,(_Float16)nf[c*2+1].z,(_Float16)nf[c*2+1].w};
                *(f16x8*)&Ks[cur ^ 1][srow * 128 + ((cc ^ (srow & 7)) * 8)] = w;
            }
        }
        __syncthreads();
        cur ^= 1;
    }

    if (l16 == 0) {
#pragma unroll
        for (int a = 0; a < 2; a++)
#pragma unroll
            for (int r2 = 0; r2 < 4; r2++) {
                int rrow = qt * 128 + wv * 32 + a * 16 + quad * 4 + r2;
                size_t g = (size_t)quarter * ROWS + (size_t)bh * SS + rrow;
                ws_m[g] = mrun[a][r2];
                ws_l[g] = lrun[a][r2];
            }
    }
}

// --------------------------------------- K3: gather + PV + LayerNorm (fused)
// One block per (b,s): all 8 heads' scores (fp16 k gather) + PV (fp16 v
// gather) + LN, entirely in-block. Kills the out HBM round-trip, the ln
// launch, and 8x of tiny-block dispatch overhead. Group g = head g (32 lanes).
__global__ __launch_bounds__(256) void attnout_ln_kernel(const float* __restrict__ q,
                                                         const _Float16* __restrict__ k16,
                                                         const _Float16* __restrict__ v16,
                                                         const int* __restrict__ idx_ws,
                                                         const float* __restrict__ ws_m,
                                                         const float* __restrict__ ws_l,
                                                         const float* __restrict__ gamma,
                                                         const float* __restrict__ beta,
                                                         float* __restrict__ out) {
    const int row = blockIdx.x;            // b*S + s, 4096 blocks
    const int b = row >> 11, s = row & 2047;
    const int t = threadIdx.x;
    const int h = t >> 5, l32 = t & 31;    // 8 head-groups of 32 lanes
    const int bh = b * HH + h;
    const int R = (bh << 11) | s;

    __shared__ __align__(16) float q_l[1024];
    __shared__ int   idx_l[8][32];
    __shared__ float e_l[8][32];
    __shared__ float w_l[8][32];
    __shared__ float mZ_l[8][2];
    __shared__ __align__(16) float o_l[1024];
    __shared__ float red[4];

    *(float4*)&q_l[t * 4] = *(const float4*)(q + (size_t)row * DD + t * 4);
    idx_l[h][l32] = idx_ws[(size_t)R * TOPK + l32];
    if (t < 8) {
        // merge 4 split-K partial stats for head t
        int Rh = ((b * HH + t) << 11) | s;
        float m = ws_m[Rh];
        m = fmaxf(m, ws_m[(size_t)ROWS + Rh]);
        m = fmaxf(m, ws_m[2 * (size_t)ROWS + Rh]);
        m = fmaxf(m, ws_m[3 * (size_t)ROWS + Rh]);
        float Z = 0.f;
#pragma unroll
        for (int qr = 0; qr < 4; ++qr)
            Z += ws_l[(size_t)qr * ROWS + Rh] * __expf(ws_m[(size_t)qr * ROWS + Rh] - m);
        mZ_l[t][0] = m;
        mZ_l[t][1] = Z;
    }
    __syncthreads();

    // scores: group h computes its 32 selected dots (fp16 k, fp32 accumulate)
    const _Float16* kbh = k16 + (size_t)bh * SS * HD;
    float4 q4 = *(const float4*)&q_l[h * HD + l32 * 4];
    const float m = mZ_l[h][0];
#pragma unroll 8
    for (int i = 0; i < 32; ++i) {
        int ki = idx_l[h][i];
        f16x4 kv = *(const f16x4*)(kbh + (size_t)ki * HD + l32 * 4);
        float d = q4.x * (float)kv[0] + q4.y * (float)kv[1]
                + q4.z * (float)kv[2] + q4.w * (float)kv[3];
#pragma unroll
        for (int off = 1; off < 32; off <<= 1) d += __shfl_xor(d, off, 64);
        if (l32 == 0) e_l[h][i] = __expf(d - m);
    }
    __syncthreads();

    // weights: thread t handles (head h, candidate l32)
    {
        float e = e_l[h][l32];
        float ssum = e;
#pragma unroll
        for (int off = 1; off < 32; off <<= 1) ssum += __shfl_xor(ssum, off, 64);
        float den = ssum + 1e-5f * mZ_l[h][1];   // = S_sel + eps*Z (exact renorm algebra)
        w_l[h][l32] = e / den;
    }
    __syncthreads();

    // PV: thread t owns head h, dims l32*4..+3
    const _Float16* vbh = v16 + (size_t)bh * SS * HD;
    float a0 = 0.f, a1 = 0.f, a2 = 0.f, a3 = 0.f;
#pragma unroll 8
    for (int i = 0; i < 32; ++i) {
        f16x4 hv = *(const f16x4*)(vbh + (size_t)idx_l[h][i] * HD + l32 * 4);
        float w = w_l[h][i];
        a0 += w * (float)hv[0];
        a1 += w * (float)hv[1];
        a2 += w * (float)hv[2];
        a3 += w * (float)hv[3];
    }
    *(float4*)&o_l[h * HD + l32 * 4] = make_float4(a0, a1, a2, a3);
    __syncthreads();

    // LayerNorm over the 1024-dim row (in LDS), write final out
    float x[4];
#pragma unroll
    for (int i = 0; i < 4; i++) x[i] = o_l[t + 256 * i];
    float sum = x[0] + x[1] + x[2] + x[3];
    const int lane = t & 63, wv = t >> 6;
    for (int off = 32; off; off >>= 1) sum += __shfl_down(sum, off, 64);
    if (lane == 0) red[wv] = sum;
    __syncthreads();
    float mean = (red[0] + red[1] + red[2] + red[3]) * (1.f / DD);
    __syncthreads();
    float vs = 0.f;
#pragma unroll
    for (int i = 0; i < 4; i++) { float d = x[i] - mean; vs += d * d; }
    for (int off = 32; off; off >>= 1) vs += __shfl_down(vs, off, 64);
    if (lane == 0) red[wv] = vs;
    __syncthreads();
    float var = (red[0] + red[1] + red[2] + red[3]) * (1.f / DD);
    float inv = rsqrtf(var + 1e-5f);
#pragma unroll
    for (int i = 0; i < 4; i++) {
        int c = t + 256 * i;
        out[(size_t)row * DD + c] = (x[i] - mean) * inv * gamma[c] + beta[c];
    }
}

extern "C" void kernel_launch(void* const* d_in, const int* in_sizes, int n_in,
                              void* d_out, int out_size, void* d_ws, size_t ws_size,
                              hipStream_t stream) {
    const float* q = (const float*)d_in[0];
    const float* k = (const float*)d_in[1];
    const float* v = (const float*)d_in[2];
    const float* aw = (const float*)d_in[3];
    const float* gamma = (const float*)d_in[4];
    const float* beta = (const float*)d_in[5];
    float* out = (float*)d_out;

    int* idx_ws = (int*)d_ws;                                        // 4 MB
    float* ws_m = (float*)((char*)d_ws + ((size_t)4 << 20));         // 512 KB
    float* ws_l = ws_m + (size_t)4 * ROWS;                           // 512 KB
    _Float16* k16 = (_Float16*)((char*)d_ws + ((size_t)8 << 20));    // 8 MB
    _Float16* v16 = k16 + (size_t)BH * SS * HD;                      // 8 MB

    hipLaunchKernelGGL(topk_cvt_kernel, dim3(NCVT + ROWS), dim3(256), 0, stream,
                       aw, k, v, k16, v16, idx_ws);
    hipLaunchKernelGGL(stats_kernel, dim3(1024), dim3(256), 0, stream, q, k, ws_m, ws_l);
    hipLaunchKernelGGL(attnout_ln_kernel, dim3(NCVT), dim3(256), 0, stream,
                       q, k16, v16, idx_ws, ws_m, ws_l, gamma, beta, out);
}

// Round 8
// 524.222 us; speedup vs baseline: 1.0148x; 1.0148x over previous
//
#include <hip/hip_runtime.h>
#include <stdint.h>

#define BB 2
#define SS 2048
#define DD 1024
#define HH 8
#define HD 128
#define TOPK 32
#define ROWS (BB*HH*SS)   // 32768
#define BH 16

typedef float f32x4 __attribute__((ext_vector_type(4)));
typedef _Float16 f16x8 __attribute__((ext_vector_type(8)));
typedef _Float16 f16x4 __attribute__((ext_vector_type(4)));

__device__ __forceinline__ void gload_lds16(const _Float16* g, _Float16* l) {
    __builtin_amdgcn_global_load_lds(
        (const __attribute__((address_space(1))) void*)g,
        (__attribute__((address_space(3))) void*)l, 16, 0, 0);
}

// ---------------------------------------------------------------- K0: fp16 preconvert
// q,k,v [B,S,D] fp32 -> head-major [bh][s][128] fp16. Same RTN cast as the old
// in-kernel staging, so stats math is bit-compatible with the verified version.
__global__ __launch_bounds__(256) void cvt_kernel(const float* __restrict__ q,
                                                  const float* __restrict__ k,
                                                  const float* __restrict__ v,
                                                  _Float16* __restrict__ q16,
                                                  _Float16* __restrict__ k16,
                                                  _Float16* __restrict__ v16) {
    const int row = blockIdx.x;              // b*S + s
    const int b = row >> 11, s = row & 2047;
    const int t = threadIdx.x;
    const int h = t >> 5, d4 = (t & 31) * 4;
    const size_t src = (size_t)row * DD + t * 4;
    const size_t dst = ((size_t)(b * HH + h) * SS + s) * HD + d4;
    float4 f;
    f = *(const float4*)(q + src);
    *(f16x4*)(q16 + dst) = (f16x4){(_Float16)f.x,(_Float16)f.y,(_Float16)f.z,(_Float16)f.w};
    f = *(const float4*)(k + src);
    *(f16x4*)(k16 + dst) = (f16x4){(_Float16)f.x,(_Float16)f.y,(_Float16)f.z,(_Float16)f.w};
    f = *(const float4*)(v + src);
    *(f16x4*)(v16 + dst) = (f16x4){(_Float16)f.x,(_Float16)f.y,(_Float16)f.z,(_Float16)f.w};
}

// ---------------------------------------------------------------- K1: top-32
// (verified; ~memory-floor on the 268 MB aw stream)
__global__ __launch_bounds__(256) void topk_kernel(const float* __restrict__ aw,
                                                   int* __restrict__ idx_out) {
    const int row = blockIdx.x;
    const float* p = aw + (size_t)row * SS;
    const int t = threadIdx.x;
    float4 v0 = *(const float4*)(p + 4 * t);
    float4 v1 = *(const float4*)(p + 1024 + 4 * t);
    float vals[8] = {v0.x, v0.y, v0.z, v0.w, v1.x, v1.y, v1.z, v1.w};
    unsigned long long key[8];
#pragma unroll
    for (int i = 0; i < 8; i++) {
        int e = (i < 4) ? (4 * t + i) : (1024 + 4 * t + (i - 4));
        unsigned u = __float_as_uint(vals[i]);
        unsigned sk = (u & 0x80000000u) ? ~u : (u | 0x80000000u);
        key[i] = ((unsigned long long)sk << 11) | (unsigned)(2047 - e);
    }
    __shared__ int s_cnt;
    __shared__ int s_red[4];
    __shared__ unsigned long long s_cand[256];
    const int lane = t & 63, wv = t >> 6;

    unsigned thr0 = __float_as_uint(1.76f) | 0x80000000u;
    unsigned long long T = ((unsigned long long)thr0 << 11) | 2047ull;

    if (t == 0) s_cnt = 0;
    __syncthreads();
#pragma unroll
    for (int i = 0; i < 8; i++) {
        if (key[i] > T) {
            int pos = atomicAdd(&s_cnt, 1);
            if (pos < 256) s_cand[pos] = key[i];
        }
    }
    __syncthreads();

    if (s_cnt < TOPK || s_cnt > 256) {
        unsigned long long lo = 0, hi = ~0ull;
        if (s_cnt > 256) lo = T; else hi = T;
        T = lo + ((hi - lo) >> 1);
        for (int it = 0; it < 40; ++it) {
            int c = 0;
#pragma unroll
            for (int i = 0; i < 8; i++) c += (key[i] > T) ? 1 : 0;
            for (int off = 32; off; off >>= 1) c += __shfl_down(c, off, 64);
            if (lane == 0) s_red[wv] = c;
            __syncthreads();
            int tot = s_red[0] + s_red[1] + s_red[2] + s_red[3];
            if (tot >= TOPK && tot <= 256) break;
            if (tot > 256) lo = T; else hi = T;
            T = lo + ((hi - lo) >> 1);
            __syncthreads();
        }
        if (t == 0) s_cnt = 0;
        __syncthreads();
#pragma unroll
        for (int i = 0; i < 8; i++) {
            if (key[i] > T) {
                int pos = atomicAdd(&s_cnt, 1);
                if (pos < 256) s_cand[pos] = key[i];
            }
        }
        __syncthreads();
    }

    const int C = s_cnt < 256 ? s_cnt : 256;
    if (t < C) {
        unsigned long long mk = s_cand[t];
        int rank = 0;
        for (int j = 0; j < C; ++j)
            rank += (s_cand[j] > mk) ? 1 : 0;
        if (rank < TOPK)
            idx_out[(size_t)row * TOPK + rank] = 2047 - (int)(mk & 2047ull);
    }
}

// ------------------------------------------------------- K2: softmax stats
// Q fragments global->register (no LDS); K fp16 staged via global_load_lds
// dwordx4 into linear LDS with a both-sides XOR-chunk swizzle (involution
// chunk ^= row&7 baked into the per-lane GLOBAL source address; LDS dest
// stays linear per rule 21). Double-buffered 64-row K tiles, prefetch-
// before-compute, 1 barrier/tile. Split-K x4; XCD-pair swizzle: XCD x
// serves only bh {2x,2x+1} (k16 slice 1 MB -> re-reads L2-resident).
__global__ __launch_bounds__(256) void stats_kernel(const _Float16* __restrict__ q16,
                                                    const _Float16* __restrict__ k16,
                                                    float* __restrict__ ws_m,
                                                    float* __restrict__ ws_l) {
    __shared__ __align__(16) _Float16 Ks[2][64 * 128];   // 2 x 16 KB
    const int xcd = blockIdx.x & 7;
    const int r = blockIdx.x >> 3;
    const int bh = xcd * 2 + (r & 1);
    const int rr = r >> 1;
    const int qt = rr & 15;
    const int quarter = rr >> 4;          // 0..3: 512 keys each
    const int t = threadIdx.x;
    const int wv = t >> 6, lane = t & 63;
    const int l16 = lane & 15, quad = lane >> 4;

    // --- Q fragments straight into registers
    const _Float16* qb = q16 + ((size_t)bh * SS + qt * 128 + wv * 32 + l16) * HD;
    f16x8 af[2][4];
#pragma unroll
    for (int a = 0; a < 2; a++)
#pragma unroll
        for (int ks = 0; ks < 4; ks++)
            af[a][ks] = *(const f16x8*)(qb + a * 16 * HD + ks * 32 + quad * 8);

    // --- per-lane staging source offsets (halves) with inverse swizzle baked in.
    const int lr = lane >> 4, lc = lane & 15;
    int srco[4];
#pragma unroll
    for (int i = 0; i < 4; i++) {
        int x = ((i & 1) * 4) + lr;
        srco[i] = (wv * 16 + i * 4 + lr) * HD + ((lc ^ x) * 8);
    }
    const _Float16* kb = k16 + (size_t)bh * SS * HD;

    // precompute swizzled read chunk offsets (halves) per ks
    int rdoff[4];
#pragma unroll
    for (int ks = 0; ks < 4; ks++)
        rdoff[ks] = (((ks * 4 + quad) ^ (l16 & 7)) * 8);

    float mrun[2][4], lrun[2][4];
#pragma unroll
    for (int a = 0; a < 2; a++)
#pragma unroll
        for (int r2 = 0; r2 < 4; r2++) { mrun[a][r2] = -INFINITY; lrun[a][r2] = 0.f; }

    // prologue: stage tile 0
    {
        const _Float16* src = kb + (size_t)(quarter * 8) * 64 * HD;
#pragma unroll
        for (int i = 0; i < 4; i++)
            gload_lds16(src + srco[i], &Ks[0][(wv * 4 + i) * 512]);
    }
    __syncthreads();   // compiler drains vmcnt(0) before barrier

    int cur = 0;
    for (int tt = 0; tt < 8; ++tt) {
        if (tt < 7) {   // prefetch next tile into the other buffer
            const _Float16* src = kb + (size_t)(quarter * 8 + tt + 1) * 64 * HD;
#pragma unroll
            for (int i = 0; i < 4; i++)
                gload_lds16(src + srco[i], &Ks[cur ^ 1][(wv * 4 + i) * 512]);
        }
        f32x4 acc[2][4];
#pragma unroll
        for (int a = 0; a < 2; a++)
#pragma unroll
            for (int n = 0; n < 4; n++) acc[a][n] = (f32x4){0.f, 0.f, 0.f, 0.f};
#pragma unroll
        for (int ks = 0; ks < 4; ++ks) {
            f16x8 bfr[4];
#pragma unroll
            for (int n = 0; n < 4; n++)
                bfr[n] = *(const f16x8*)&Ks[cur][(n * 16 + l16) * HD + rdoff[ks]];
#pragma unroll
            for (int a = 0; a < 2; a++)
#pragma unroll
                for (int n = 0; n < 4; n++)
                    acc[a][n] = __builtin_amdgcn_mfma_f32_16x16x32_f16(af[a][ks], bfr[n], acc[a][n], 0, 0, 0);
        }
        // online max / sumexp per row (row = wv*32 + a*16 + quad*4 + r2)
#pragma unroll
        for (int a = 0; a < 2; a++) {
#pragma unroll
            for (int r2 = 0; r2 < 4; r2++) {
                float tm = fmaxf(fmaxf(acc[a][0][r2], acc[a][1][r2]),
                                 fmaxf(acc[a][2][r2], acc[a][3][r2]));
#pragma unroll
                for (int off = 1; off < 16; off <<= 1) tm = fmaxf(tm, __shfl_xor(tm, off, 64));
                float tl = 0.f;
#pragma unroll
                for (int n = 0; n < 4; n++) tl += __expf(acc[a][n][r2] - tm);
#pragma unroll
                for (int off = 1; off < 16; off <<= 1) tl += __shfl_xor(tl, off, 64);
                float mo = mrun[a][r2];
                float mn = fmaxf(mo, tm);
                lrun[a][r2] = lrun[a][r2] * __expf(mo - mn) + tl * __expf(tm - mn);
                mrun[a][r2] = mn;
            }
        }
        __syncthreads();   // next tile staged + everyone done with Ks[cur]
        cur ^= 1;
    }

    if (l16 == 0) {
#pragma unroll
        for (int a = 0; a < 2; a++)
#pragma unroll
            for (int r2 = 0; r2 < 4; r2++) {
                int rrow = qt * 128 + wv * 32 + a * 16 + quad * 4 + r2;
                size_t g = (size_t)quarter * ROWS + (size_t)bh * SS + rrow;
                ws_m[g] = mrun[a][r2];
                ws_l[g] = lrun[a][r2];
            }
    }
}

// --------------------------------------------- K2b: gather scores + PV
// Scores stay fp32 (accuracy); PV gathers fp16 v16 at float4 granularity.
// Per-XCD working set: 2x k fp32 (2 MB) + 2x v16 (1 MB) = 3 MB < 4 MB L2.
__global__ __launch_bounds__(128) void attnout_kernel(const float* __restrict__ q,
                                                      const float* __restrict__ k,
                                                      const _Float16* __restrict__ v16,
                                                      const int* __restrict__ idx_ws,
                                                      const float* __restrict__ ws_m,
                                                      const float* __restrict__ ws_l,
                                                      float* __restrict__ out) {
    const int bh = blockIdx.x & 15;
    const int s = blockIdx.x >> 4;
    const int R = (bh << 11) | s;
    const int b = bh >> 3, h = bh & 7;
    const int t = threadIdx.x;
    __shared__ float q_l[128];
    __shared__ int idx_l[32];
    __shared__ float e_l[32];
    __shared__ float w_l[32];
    __shared__ __align__(16) float s_pv[4][128];
    const float* qrow = q + ((size_t)(b * SS + s) * DD + h * HD);
    q_l[t] = qrow[t];
    if (t < 32) idx_l[t] = idx_ws[(size_t)R * TOPK + t];
    __syncthreads();
    // merge 4 split-K partial stats
    float m = ws_m[R];
    m = fmaxf(m, ws_m[(size_t)ROWS + R]);
    m = fmaxf(m, ws_m[2 * (size_t)ROWS + R]);
    m = fmaxf(m, ws_m[3 * (size_t)ROWS + R]);
    float Z = 0.f;
#pragma unroll
    for (int qr = 0; qr < 4; ++qr)
        Z += ws_l[(size_t)qr * ROWS + R] * __expf(ws_m[(size_t)qr * ROWS + R] - m);

    const int l32 = t & 31, g = t >> 5;   // 4 groups of 32 lanes
    float4 q4 = *(const float4*)&q_l[l32 * 4];
    const float* kb = k + ((size_t)b * SS * DD + h * HD);
#pragma unroll
    for (int p = 0; p < 8; ++p) {
        int i = p * 4 + g;
        int ki = idx_l[i];
        float4 kv = *(const float4*)(kb + (size_t)ki * DD + l32 * 4);
        float d = q4.x * kv.x + q4.y * kv.y + q4.z * kv.z + q4.w * kv.w;
#pragma unroll
        for (int off = 1; off < 32; off <<= 1) d += __shfl_xor(d, off, 64);
        if (l32 == 0) e_l[i] = __expf(d - m);
    }
    __syncthreads();
    if (t < 32) {
        float e = e_l[t];
        float ssum = e;
#pragma unroll
        for (int off = 1; off < 32; off <<= 1) ssum += __shfl_xor(ssum, off, 64);
        float den = ssum + 1e-5f * Z;     // = S_sel + eps*Z (exact renorm algebra)
        w_l[t] = e / den;
    }
    __syncthreads();
    const _Float16* vb = v16 + (size_t)bh * SS * HD;
    float a0 = 0.f, a1 = 0.f, a2 = 0.f, a3 = 0.f;
#pragma unroll
    for (int p = 0; p < 8; ++p) {
        int i = p * 4 + g;
        f16x4 hv = *(const f16x4*)(vb + (size_t)idx_l[i] * HD + l32 * 4);
        float w = w_l[i];
        a0 += w * (float)hv[0];
        a1 += w * (float)hv[1];
        a2 += w * (float)hv[2];
        a3 += w * (float)hv[3];
    }
    *(float4*)&s_pv[g][l32 * 4] = make_float4(a0, a1, a2, a3);
    __syncthreads();
    out[((size_t)(b * SS + s) * DD) + h * HD + t] =
        s_pv[0][t] + s_pv[1][t] + s_pv[2][t] + s_pv[3][t];
}

// ----------------------------------------------------- K3: LayerNorm in-place
__global__ __launch_bounds__(256) void ln_kernel(float* __restrict__ out,
                                                 const float* __restrict__ gamma,
                                                 const float* __restrict__ beta) {
    const int row = blockIdx.x;   // B*S = 4096
    float* p = out + (size_t)row * DD;
    const int t = threadIdx.x;
    float x[4];
#pragma unroll
    for (int i = 0; i < 4; i++) x[i] = p[t + 256 * i];
    float sum = x[0] + x[1] + x[2] + x[3];
    __shared__ float red[4];
    const int lane = t & 63, wv = t >> 6;
    for (int off = 32; off; off >>= 1) sum += __shfl_down(sum, off, 64);
    if (lane == 0) red[wv] = sum;
    __syncthreads();
    float mean = (red[0] + red[1] + red[2] + red[3]) * (1.f / DD);
    __syncthreads();
    float vs = 0.f;
#pragma unroll
    for (int i = 0; i < 4; i++) { float d = x[i] - mean; vs += d * d; }
    for (int off = 32; off; off >>= 1) vs += __shfl_down(vs, off, 64);
    if (lane == 0) red[wv] = vs;
    __syncthreads();
    float var = (red[0] + red[1] + red[2] + red[3]) * (1.f / DD);
    float inv = rsqrtf(var + 1e-5f);
#pragma unroll
    for (int i = 0; i < 4; i++) {
        int c = t + 256 * i;
        p[c] = (x[i] - mean) * inv * gamma[c] + beta[c];
    }
}

extern "C" void kernel_launch(void* const* d_in, const int* in_sizes, int n_in,
                              void* d_out, int out_size, void* d_ws, size_t ws_size,
                              hipStream_t stream) {
    const float* q = (const float*)d_in[0];
    const float* k = (const float*)d_in[1];
    const float* v = (const float*)d_in[2];
    const float* aw = (const float*)d_in[3];
    const float* gamma = (const float*)d_in[4];
    const float* beta = (const float*)d_in[5];
    float* out = (float*)d_out;

    int* idx_ws = (int*)d_ws;                                        // 4 MB
    float* ws_m = (float*)((char*)d_ws + ((size_t)4 << 20));         // 512 KB
    float* ws_l = ws_m + (size_t)4 * ROWS;                           // 512 KB
    _Float16* q16 = (_Float16*)((char*)d_ws + ((size_t)8 << 20));    // 8 MB
    _Float16* k16 = q16 + (size_t)BH * SS * HD;                      // 8 MB
    _Float16* v16 = k16 + (size_t)BH * SS * HD;                      // 8 MB

    hipLaunchKernelGGL(cvt_kernel, dim3(BB * SS), dim3(256), 0, stream, q, k, v, q16, k16, v16);
    hipLaunchKernelGGL(topk_kernel, dim3(ROWS), dim3(256), 0, stream, aw, idx_ws);
    hipLaunchKernelGGL(stats_kernel, dim3(1024), dim3(256), 0, stream, q16, k16, ws_m, ws_l);
    hipLaunchKernelGGL(attnout_kernel, dim3(ROWS), dim3(128), 0, stream, q, k, v16, idx_ws, ws_m, ws_l, out);
    hipLaunchKernelGGL(ln_kernel, dim3(BB * SS), dim3(256), 0, stream, out, gamma, beta);
}